// Round 14
// baseline (100.464 us; speedup 1.0000x reference)
//
#include <hip/hip_runtime.h>

typedef short  bf16x8 __attribute__((ext_vector_type(8)));

#define CHUNK_TILES 32                    // 32 j-tiles per LDS chunk (32 KB)
#define CHUNKS      25
#define TOTTILES    (CHUNK_TILES * CHUNKS)   // 800 tiles = 25600 rows (>= 25000)
#define MROWS       (TOTTILES * 32)

__device__ __forceinline__ unsigned short f2bf(float x) {
    unsigned u = __builtin_bit_cast(unsigned, x);
    u += 0x7FFF + ((u >> 16) & 1);          // RNE
    return (unsigned short)(u >> 16);
}
__device__ __forceinline__ float bf2f(unsigned short h) {
    unsigned u = ((unsigned)h) << 16;
    return __builtin_bit_cast(float, u);
}

// ---- pack padding points into tile-major MFMA-A layout in ws ----
// Tile T, row n, plane h: ws bytes T*1024 + h*512 + n*16 (uint4: T*64 + h*32 + n).
// Row: k0-2 qh | k3-5 ql | k6-8 qh | k9-11 ql | k12-13 negc h/l | k14-15 1.0,1.0.
// Rows >= M get negc=-1e6: sign -1 cancels the +1 baseline (self-canceling pad).
__global__ __launch_bounds__(256) void dens_pack_kernel(
    const float* __restrict__ pad, uint4* __restrict__ ws, int M)
{
    const int j = blockIdx.x * 256 + threadIdx.x;
    if (j >= MROWS) return;

    float qx = 0.f, qy = 0.f, qz = 0.f;
    float negc = -1.0e6f;
    if (j < M) {
        qx = pad[3 * j]; qy = pad[3 * j + 1]; qz = pad[3 * j + 2];
        negc = 0.125f - 0.5f * (qx * qx + qy * qy + qz * qz);   // (r^2 - |q|^2)/2
    }
    const unsigned short xh = f2bf(qx), yh = f2bf(qy), zh = f2bf(qz);
    const unsigned short xl = f2bf(qx - bf2f(xh));
    const unsigned short yl = f2bf(qy - bf2f(yh));
    const unsigned short zl = f2bf(qz - bf2f(zh));
    const unsigned short ch = f2bf(negc);
    const unsigned short cl = f2bf(negc - bf2f(ch));

    uint4 p0, p1;
    p0.x = (unsigned)xh | ((unsigned)yh << 16);   // k0,k1
    p0.y = (unsigned)zh | ((unsigned)xl << 16);   // k2,k3
    p0.z = (unsigned)yl | ((unsigned)zl << 16);   // k4,k5
    p0.w = (unsigned)xh | ((unsigned)yh << 16);   // k6,k7
    p1.x = (unsigned)zh | ((unsigned)xl << 16);   // k8,k9
    p1.y = (unsigned)yl | ((unsigned)zl << 16);   // k10,k11
    p1.z = (unsigned)ch | ((unsigned)cl << 16);   // k12,k13
    p1.w = 0x3F803F80u;                           // k14,k15 = 1.0,1.0
    const int T = j >> 5, n = j & 31;
    ws[T * 64 + n]      = p0;                     // plane0
    ws[T * 64 + 32 + n] = p1;                     // plane1
}

// B-frag with threshold folded into k14/k15 (R13-proven, absmax 64):
// s = p.q + negc - ha ; within <=> sign(s) == 0.
__device__ __forceinline__ void make_bfrag(const float* __restrict__ pc,
                                           int i, int N, int half, bf16x8& B)
{
    float px = 0.f, py = 0.f, pz = 0.f;
    float ha = 3.0e38f;
    if (i < N) {
        px = pc[3 * i]; py = pc[3 * i + 1]; pz = pc[3 * i + 2];
        ha = 0.5f * (px * px + py * py + pz * pz);
    }
    const float nha = -ha;
    const unsigned short nhh = f2bf(nha);
    const unsigned short nhl = f2bf(nha - bf2f(nhh));
    const short xh = (short)f2bf(px), yh = (short)f2bf(py), zh = (short)f2bf(pz);
    const short xl = (short)f2bf(px - bf2f((unsigned short)xh));
    const short yl = (short)f2bf(py - bf2f((unsigned short)yh));
    const short zl = (short)f2bf(pz - bf2f((unsigned short)zh));
    const short ONE = (short)0x3F80;
    const bf16x8 Blo = {xh, yh, zh, xh, yh, zh, xl, yl};
    const bf16x8 Bhi = {zl, xl, yl, zl, ONE, ONE, (short)nhh, (short)nhl};
    B = half ? Bhi : Blo;
}

// consume one 16-elem D group: 16 in-place sign-extracts + 8 v_add3 (full-rate).
#define CONS(R0,R1,R2,R3,R4,R5,R6,R7,R8,R9,RA,RB,RC,RD,RE,RF, CA, CB) \
    "v_ashrrev_i32 " R0 ", 31, " R0 "\n\t" \
    "v_ashrrev_i32 " R1 ", 31, " R1 "\n\t" \
    "v_ashrrev_i32 " R2 ", 31, " R2 "\n\t" \
    "v_ashrrev_i32 " R3 ", 31, " R3 "\n\t" \
    "v_ashrrev_i32 " R4 ", 31, " R4 "\n\t" \
    "v_ashrrev_i32 " R5 ", 31, " R5 "\n\t" \
    "v_ashrrev_i32 " R6 ", 31, " R6 "\n\t" \
    "v_ashrrev_i32 " R7 ", 31, " R7 "\n\t" \
    "v_ashrrev_i32 " R8 ", 31, " R8 "\n\t" \
    "v_ashrrev_i32 " R9 ", 31, " R9 "\n\t" \
    "v_ashrrev_i32 " RA ", 31, " RA "\n\t" \
    "v_ashrrev_i32 " RB ", 31, " RB "\n\t" \
    "v_ashrrev_i32 " RC ", 31, " RC "\n\t" \
    "v_ashrrev_i32 " RD ", 31, " RD "\n\t" \
    "v_ashrrev_i32 " RE ", 31, " RE "\n\t" \
    "v_ashrrev_i32 " RF ", 31, " RF "\n\t" \
    "v_add3_u32 " CA ", " R0 ", " R1 ", " CA "\n\t" \
    "v_add3_u32 " CB ", " R2 ", " R3 ", " CB "\n\t" \
    "v_add3_u32 " CA ", " R4 ", " R5 ", " CA "\n\t" \
    "v_add3_u32 " CB ", " R6 ", " R7 ", " CB "\n\t" \
    "v_add3_u32 " CA ", " R8 ", " R9 ", " CA "\n\t" \
    "v_add3_u32 " CB ", " RA ", " RB ", " CB "\n\t" \
    "v_add3_u32 " CA ", " RC ", " RD ", " CA "\n\t" \
    "v_add3_u32 " CB ", " RE ", " RF ", " CB "\n\t"

#define CONS_D0(CA, CB) \
    CONS("v32","v33","v34","v35","v36","v37","v38","v39", \
         "v40","v41","v42","v43","v44","v45","v46","v47", CA, CB)
#define CONS_D1(CA, CB) \
    CONS("v48","v49","v50","v51","v52","v53","v54","v55", \
         "v56","v57","v58","v59","v60","v61","v62","v63", CA, CB)

// grid 625 x 1, 512 thr (8 waves). Each block owns one 32-i column end-to-end:
// NO atomics, NO output pre-zero, NO global loads in the MFMA loop.
// Per chunk: regs->LDS stage, barrier, prefetch next chunk regs, asm compute
// (4 ds_read_b128 + 4 MFMA + sign-count from LDS), barrier.
// Physical asm map: d0=v[32:47] d1=v[48:63] C0=v[64:79] A0..A3=v[80:95].
__global__ __launch_bounds__(512, 4) void dens_mfma_kernel(
    const float* __restrict__ pc,     // [N,3] pointcloud
    const uint4* __restrict__ wsA,    // packed tiles (tile-major)
    int* __restrict__ out, int N)
{
    __shared__ uint4 stage[2048];     // 32 KB: one chunk (32 tiles)
    __shared__ int   red[8][32];

    const int tid  = threadIdx.x;
    const int lane = tid & 63;
    const int w    = tid >> 6;        // wave 0..7
    const int n    = lane & 31;       // output col = i within tile
    const int half = lane >> 5;       // k-chunk 0/1

    bf16x8 B;
    make_bfrag(pc, blockIdx.x * 32 + n, N, half, B);

    // LDS byte address for this lane's A-frag of its first tile in a chunk:
    // tile (w + 8k) at base + k*8192, k=0..3 (imm offsets).
    const unsigned lds_base =
        (unsigned)(unsigned long long)(&stage[0]) + (unsigned)(w * 1024 + half * 512 + n * 16);

    // prime: chunk 0 into registers
    uint4 r0 = wsA[tid],       r1 = wsA[512 + tid];
    uint4 r2 = wsA[1024 + tid], r3 = wsA[1536 + tid];

    int cA = 0, cB = 0;

    for (int c = 0; c < CHUNKS; ++c) {
        stage[tid] = r0; stage[512 + tid] = r1;
        stage[1024 + tid] = r2; stage[1536 + tid] = r3;
        __syncthreads();
        if (c + 1 < CHUNKS) {                 // prefetch next chunk (flies under asm)
            const int b = (c + 1) * 2048 + tid;
            r0 = wsA[b]; r1 = wsA[b + 512]; r2 = wsA[b + 1024]; r3 = wsA[b + 1536];
        }
        asm volatile(
            "v_mov_b32 v64, 0\n\t" "v_mov_b32 v65, 0\n\t"
            "v_mov_b32 v66, 0\n\t" "v_mov_b32 v67, 0\n\t"
            "v_mov_b32 v68, 0\n\t" "v_mov_b32 v69, 0\n\t"
            "v_mov_b32 v70, 0\n\t" "v_mov_b32 v71, 0\n\t"
            "v_mov_b32 v72, 0\n\t" "v_mov_b32 v73, 0\n\t"
            "v_mov_b32 v74, 0\n\t" "v_mov_b32 v75, 0\n\t"
            "v_mov_b32 v76, 0\n\t" "v_mov_b32 v77, 0\n\t"
            "v_mov_b32 v78, 0\n\t" "v_mov_b32 v79, 0\n\t"
            "ds_read_b128 v[80:83], %3\n\t"
            "ds_read_b128 v[84:87], %3 offset:8192\n\t"
            "ds_read_b128 v[88:91], %3 offset:16384\n\t"
            "ds_read_b128 v[92:95], %3 offset:24576\n\t"
            "s_waitcnt lgkmcnt(2)\n\t"
            "v_mfma_f32_32x32x16_bf16 v[32:47], v[80:83], %2, v[64:79]\n\t"
            "v_mfma_f32_32x32x16_bf16 v[48:63], v[84:87], %2, v[64:79]\n\t"
            "s_nop 7\n\t"
            "s_nop 2\n\t"
            CONS_D0("%0", "%1")
            "s_waitcnt lgkmcnt(0)\n\t"
            "v_mfma_f32_32x32x16_bf16 v[32:47], v[88:91], %2, v[64:79]\n\t"
            CONS_D1("%0", "%1")
            "v_mfma_f32_32x32x16_bf16 v[48:63], v[92:95], %2, v[64:79]\n\t"
            "s_nop 7\n\t"
            "s_nop 2\n\t"
            CONS_D0("%0", "%1")
            CONS_D1("%0", "%1")
            : "+v"(cA), "+v"(cB)
            : "v"(B), "v"(lds_base)
            : "memory",
              "v32","v33","v34","v35","v36","v37","v38","v39",
              "v40","v41","v42","v43","v44","v45","v46","v47",
              "v48","v49","v50","v51","v52","v53","v54","v55",
              "v56","v57","v58","v59","v60","v61","v62","v63",
              "v64","v65","v66","v67","v68","v69","v70","v71",
              "v72","v73","v74","v75","v76","v77","v78","v79",
              "v80","v81","v82","v83","v84","v85","v86","v87",
              "v88","v89","v90","v91","v92","v93","v94","v95");
        __syncthreads();
    }

    // per lane-half: 100 tiles x 16 elems baseline + sign-sums
    int t = 1600 + cA + cB;
    t += __shfl_xor(t, 32);               // column total for this wave (3200 + signs)
    if (lane < 32) red[w][n] = t;
    __syncthreads();
    if (tid < 32) {
        const int ii = blockIdx.x * 32 + tid;
        if (ii < N) {
            int s = 0;
            #pragma unroll
            for (int k = 0; k < 8; ++k) s += red[k][tid];
            out[ii] = s;                  // 25600 baseline included; pads self-cancel
        }
    }
}

extern "C" void kernel_launch(void* const* d_in, const int* in_sizes, int n_in,
                              void* d_out, int out_size, void* d_ws, size_t ws_size,
                              hipStream_t stream) {
    const float* pc  = (const float*)d_in[0];   // [N,3] pointcloud
    const float* pad = (const float*)d_in[1];   // [M,3] pointcloud_padding
    int* out = (int*)d_out;

    const int N = in_sizes[0] / 3;              // 20000
    const int M = in_sizes[1] / 3;              // 25000

    dens_pack_kernel<<<(MROWS + 255) / 256, 256, 0, stream>>>(
        pad, (uint4*)d_ws, M);                  // 800 tiles, ~819 KB in ws

    dens_mfma_kernel<<<(N + 31) / 32, 512, 0, stream>>>(
        pc, (const uint4*)d_ws, out, N);        // 625 blocks x 8 waves
}

// Round 16
// 86.094 us; speedup vs baseline: 1.1669x; 1.1669x over previous
//
#include <hip/hip_runtime.h>

typedef short  bf16x8 __attribute__((ext_vector_type(8)));

#define JS      13           // j-splits (grid.y)
#define STREAMS (JS * 4)     // 52 wave-streams per i-tile (stride in j-tiles)
#define TI      128          // i-points per block (4 MFMA groups per A-load)
#define DEPTH   2            // prefetch depth (buffers X/Y)

__device__ __forceinline__ unsigned short f2bf(float x) {
    unsigned u = __builtin_bit_cast(unsigned, x);
    u += 0x7FFF + ((u >> 16) & 1);          // RNE
    return (unsigned short)(u >> 16);
}
__device__ __forceinline__ float bf2f(unsigned short h) {
    unsigned u = ((unsigned)h) << 16;
    return __builtin_bit_cast(float, u);
}

// ---- pack padding points into MFMA-A planes + zero the output ----
// Row j (K=16 bf16): k0-2 qh | k3-5 ql | k6-8 qh | k9-11 ql | k12-13 negc h/l |
// k14-15 = 1.0,1.0 (pairs with B's -ha hi/lo threshold fold).
// plane0 = k0-7 (lanes 0-31), plane1 = k8-15 (lanes 32-63).
// Pad rows (j >= M): negc=-1e6 -> s<0 -> sign -1 cancels the +1 baseline.
__global__ __launch_bounds__(256) void dens_pack_kernel(
    const float* __restrict__ pad, uint4* __restrict__ ws,
    int* __restrict__ out, int M, int mtot, int N)
{
    const int j = blockIdx.x * 256 + threadIdx.x;
    if (j < N) out[j] = 0;                      // fold output zeroing here
    if (j >= mtot) return;

    float qx = 0.f, qy = 0.f, qz = 0.f;
    float negc = -1.0e6f;
    if (j < M) {
        qx = pad[3 * j]; qy = pad[3 * j + 1]; qz = pad[3 * j + 2];
        negc = 0.125f - 0.5f * (qx * qx + qy * qy + qz * qz);   // (r^2 - |q|^2)/2
    }
    const unsigned short xh = f2bf(qx), yh = f2bf(qy), zh = f2bf(qz);
    const unsigned short xl = f2bf(qx - bf2f(xh));
    const unsigned short yl = f2bf(qy - bf2f(yh));
    const unsigned short zl = f2bf(qz - bf2f(zh));
    const unsigned short ch = f2bf(negc);
    const unsigned short cl = f2bf(negc - bf2f(ch));

    uint4 p0, p1;
    p0.x = (unsigned)xh | ((unsigned)yh << 16);   // k0,k1
    p0.y = (unsigned)zh | ((unsigned)xl << 16);   // k2,k3
    p0.z = (unsigned)yl | ((unsigned)zl << 16);   // k4,k5
    p0.w = (unsigned)xh | ((unsigned)yh << 16);   // k6,k7
    p1.x = (unsigned)zh | ((unsigned)xl << 16);   // k8,k9
    p1.y = (unsigned)yl | ((unsigned)zl << 16);   // k10,k11
    p1.z = (unsigned)ch | ((unsigned)cl << 16);   // k12,k13
    p1.w = 0x3F803F80u;                           // k14,k15 = 1.0,1.0
    ws[j]        = p0;                            // plane0
    ws[mtot + j] = p1;                            // plane1
}

// B-frag with threshold folded into k14/k15 (R13-proven, absmax 64):
// s = p.q + negc - ha ; within <=> sign(s) == 0.
__device__ __forceinline__ void make_bfrag(const float* __restrict__ pc,
                                           int i, int N, int half, bf16x8& B)
{
    float px = 0.f, py = 0.f, pz = 0.f;
    float ha = 3.0e38f;                          // i-pad: s<0 always (discarded at write)
    if (i < N) {
        px = pc[3 * i]; py = pc[3 * i + 1]; pz = pc[3 * i + 2];
        ha = 0.5f * (px * px + py * py + pz * pz);
    }
    const float nha = -ha;
    const unsigned short nhh = f2bf(nha);
    const unsigned short nhl = f2bf(nha - bf2f(nhh));
    const short xh = (short)f2bf(px), yh = (short)f2bf(py), zh = (short)f2bf(pz);
    const short xl = (short)f2bf(px - bf2f((unsigned short)xh));
    const short yl = (short)f2bf(py - bf2f((unsigned short)yh));
    const short zl = (short)f2bf(pz - bf2f((unsigned short)zh));
    const short ONE = (short)0x3F80;
    const bf16x8 Blo = {xh, yh, zh, xh, yh, zh, xl, yl};
    const bf16x8 Bhi = {zl, xl, yl, zl, ONE, ONE, (short)nhh, (short)nhl};
    B = half ? Bhi : Blo;
}

// consume one 16-elem D group: 16 in-place sign-extracts + 8 v_add3.
#define CONS(R0,R1,R2,R3,R4,R5,R6,R7,R8,R9,RA,RB,RC,RD,RE,RF, CA, CB) \
    "v_ashrrev_i32 " R0 ", 31, " R0 "\n\t" \
    "v_ashrrev_i32 " R1 ", 31, " R1 "\n\t" \
    "v_ashrrev_i32 " R2 ", 31, " R2 "\n\t" \
    "v_ashrrev_i32 " R3 ", 31, " R3 "\n\t" \
    "v_ashrrev_i32 " R4 ", 31, " R4 "\n\t" \
    "v_ashrrev_i32 " R5 ", 31, " R5 "\n\t" \
    "v_ashrrev_i32 " R6 ", 31, " R6 "\n\t" \
    "v_ashrrev_i32 " R7 ", 31, " R7 "\n\t" \
    "v_ashrrev_i32 " R8 ", 31, " R8 "\n\t" \
    "v_ashrrev_i32 " R9 ", 31, " R9 "\n\t" \
    "v_ashrrev_i32 " RA ", 31, " RA "\n\t" \
    "v_ashrrev_i32 " RB ", 31, " RB "\n\t" \
    "v_ashrrev_i32 " RC ", 31, " RC "\n\t" \
    "v_ashrrev_i32 " RD ", 31, " RD "\n\t" \
    "v_ashrrev_i32 " RE ", 31, " RE "\n\t" \
    "v_ashrrev_i32 " RF ", 31, " RF "\n\t" \
    "v_add3_u32 " CA ", " R0 ", " R1 ", " CA "\n\t" \
    "v_add3_u32 " CB ", " R2 ", " R3 ", " CB "\n\t" \
    "v_add3_u32 " CA ", " R4 ", " R5 ", " CA "\n\t" \
    "v_add3_u32 " CB ", " R6 ", " R7 ", " CB "\n\t" \
    "v_add3_u32 " CA ", " R8 ", " R9 ", " CA "\n\t" \
    "v_add3_u32 " CB ", " RA ", " RB ", " CB "\n\t" \
    "v_add3_u32 " CA ", " RC ", " RD ", " CA "\n\t" \
    "v_add3_u32 " CB ", " RE ", " RF ", " CB "\n\t"

#define CONS_D0(CA, CB) \
    CONS("v32","v33","v34","v35","v36","v37","v38","v39", \
         "v40","v41","v42","v43","v44","v45","v46","v47", CA, CB)
#define CONS_D1(CA, CB) \
    CONS("v48","v49","v50","v51","v52","v53","v54","v55", \
         "v56","v57","v58","v59","v60","v61","v62","v63", CA, CB)

// Cross-slot software-pipelined visit: each consume group reads a D written
// ~25 instrs (>=50 cyc) earlier -> NO s_nops, no MFMA-latency exposure.
// Slot map (steady state): G(d0=prevB2)->c2, M(d0<-A*B0), G(d1=prevB3)->c3,
// M(d1<-A*B1), G(d0=B0)->c0, M(d0<-A*B2), G(d1=B1)->c1, M(d1<-A*B3), load AR.
// d0/d1 zero-init in preamble: first two consumes read +0.0 (sign 0, adds 0).
#define VISIT(AR) \
    CONS_D0("%4", "%5") \
    "s_waitcnt vmcnt(1)\n\t" \
    "v_mfma_f32_32x32x16_bf16 v[32:47], " AR ", %9,  v[64:79]\n\t" \
    CONS_D1("%6", "%7") \
    "v_mfma_f32_32x32x16_bf16 v[48:63], " AR ", %10, v[64:79]\n\t" \
    CONS_D0("%0", "%1") \
    "v_mfma_f32_32x32x16_bf16 v[32:47], " AR ", %11, v[64:79]\n\t" \
    CONS_D1("%2", "%3") \
    "v_mfma_f32_32x32x16_bf16 v[48:63], " AR ", %12, v[64:79]\n\t" \
    "global_load_dwordx4 " AR ", v[88:89], off\n\t" \
    "v_add_co_u32 v88, vcc, 0x6800, v88\n\t" \
    "v_addc_co_u32 v89, vcc, 0, v89, vcc\n\t"

// grid (157 x 13), 256 thr. 128-wide i-tile; 52 wave-streams stride j-tiles.
// Physical map: d0=v[32:47] d1=v[48:63] Z=v[64:79] X=v[80:83] Y=v[84:87]
//               addr=v[88:89] (marching). 16 visits, 8 loop iterations + drain.
__global__ __launch_bounds__(256, 4) void dens_mfma_kernel(
    const float* __restrict__ pc,     // [N,3] pointcloud
    const char*  __restrict__ wsA,    // packed A planes ((visits+DEPTH)*STREAMS tiles)
    int* __restrict__ out,            // [N] counts (pre-zeroed)
    int N, int iters, int p1off, int visits)
{
    const int lane = threadIdx.x & 63;
    const int w    = threadIdx.x >> 6;   // wave 0..3
    const int n    = lane & 31;          // output col within 32-tile = i
    const int half = lane >> 5;          // k-chunk 0/1

    const int ibase = blockIdx.x * TI;
    bf16x8 B0, B1, B2, B3;
    make_bfrag(pc, ibase + n,      N, half, B0);
    make_bfrag(pc, ibase + 32 + n, N, half, B1);
    make_bfrag(pc, ibase + 64 + n, N, half, B2);
    make_bfrag(pc, ibase + 96 + n, N, half, B3);

    const int stream = blockIdx.y * 4 + w;          // 0..51
    const unsigned long long ax =
        (unsigned long long)(wsA + (half ? p1off : 0) + n * 16 + (size_t)stream * 512);
    const unsigned xlo = (unsigned)ax, xhi = (unsigned)(ax >> 32);

    int it = iters;
    int c0a = 0, c0b = 0, c1a = 0, c1b = 0, c2a = 0, c2b = 0, c3a = 0, c3b = 0;

    asm volatile(
        // ---- preamble: addr, Z=0 bank, d0/d1 = +0.0 (pipeline primer), 2 loads ----
        "v_mov_b32 v88, %13\n\t"
        "v_mov_b32 v89, %14\n\t"
        "v_mov_b32 v32, 0\n\t" "v_mov_b32 v33, 0\n\t"
        "v_mov_b32 v34, 0\n\t" "v_mov_b32 v35, 0\n\t"
        "v_mov_b32 v36, 0\n\t" "v_mov_b32 v37, 0\n\t"
        "v_mov_b32 v38, 0\n\t" "v_mov_b32 v39, 0\n\t"
        "v_mov_b32 v40, 0\n\t" "v_mov_b32 v41, 0\n\t"
        "v_mov_b32 v42, 0\n\t" "v_mov_b32 v43, 0\n\t"
        "v_mov_b32 v44, 0\n\t" "v_mov_b32 v45, 0\n\t"
        "v_mov_b32 v46, 0\n\t" "v_mov_b32 v47, 0\n\t"
        "v_mov_b32 v48, 0\n\t" "v_mov_b32 v49, 0\n\t"
        "v_mov_b32 v50, 0\n\t" "v_mov_b32 v51, 0\n\t"
        "v_mov_b32 v52, 0\n\t" "v_mov_b32 v53, 0\n\t"
        "v_mov_b32 v54, 0\n\t" "v_mov_b32 v55, 0\n\t"
        "v_mov_b32 v56, 0\n\t" "v_mov_b32 v57, 0\n\t"
        "v_mov_b32 v58, 0\n\t" "v_mov_b32 v59, 0\n\t"
        "v_mov_b32 v60, 0\n\t" "v_mov_b32 v61, 0\n\t"
        "v_mov_b32 v62, 0\n\t" "v_mov_b32 v63, 0\n\t"
        "v_mov_b32 v64, 0\n\t" "v_mov_b32 v65, 0\n\t"
        "v_mov_b32 v66, 0\n\t" "v_mov_b32 v67, 0\n\t"
        "v_mov_b32 v68, 0\n\t" "v_mov_b32 v69, 0\n\t"
        "v_mov_b32 v70, 0\n\t" "v_mov_b32 v71, 0\n\t"
        "v_mov_b32 v72, 0\n\t" "v_mov_b32 v73, 0\n\t"
        "v_mov_b32 v74, 0\n\t" "v_mov_b32 v75, 0\n\t"
        "v_mov_b32 v76, 0\n\t" "v_mov_b32 v77, 0\n\t"
        "v_mov_b32 v78, 0\n\t" "v_mov_b32 v79, 0\n\t"
        "global_load_dwordx4 v[80:83], v[88:89], off\n\t"
        "v_add_co_u32 v88, vcc, 0x6800, v88\n\t"
        "v_addc_co_u32 v89, vcc, 0, v89, vcc\n\t"
        "global_load_dwordx4 v[84:87], v[88:89], off\n\t"
        "v_add_co_u32 v88, vcc, 0x6800, v88\n\t"
        "v_addc_co_u32 v89, vcc, 0, v89, vcc\n\t"
        "Ldens%=:\n\t"
        VISIT("v[80:83]")
        VISIT("v[84:87]")
        "s_sub_u32 %8, %8, 1\n\t"
        "s_cmp_lg_u32 %8, 0\n\t"
        "s_cbranch_scc1 Ldens%=\n\t"
        // ---- drain: d0 holds last A*B2, d1 holds last A*B3 ----
        CONS_D0("%4", "%5")
        CONS_D1("%6", "%7")
        : "+v"(c0a), "+v"(c0b), "+v"(c1a), "+v"(c1b),
          "+v"(c2a), "+v"(c2b), "+v"(c3a), "+v"(c3b), "+s"(it)
        : "v"(B0), "v"(B1), "v"(B2), "v"(B3), "v"(xlo), "v"(xhi)
        : "vcc", "scc", "memory",
          "v32","v33","v34","v35","v36","v37","v38","v39",
          "v40","v41","v42","v43","v44","v45","v46","v47",
          "v48","v49","v50","v51","v52","v53","v54","v55",
          "v56","v57","v58","v59","v60","v61","v62","v63",
          "v64","v65","v66","v67","v68","v69","v70","v71",
          "v72","v73","v74","v75","v76","v77","v78","v79",
          "v80","v81","v82","v83","v84","v85","v86","v87",
          "v88","v89");

    // per-column count = 32*visits + sign-sums; combine halves (lanes n, n+32)
    const int base = 32 * visits;
    int t0 = c0a + c0b;  t0 += __shfl_xor(t0, 32);
    int t1 = c1a + c1b;  t1 += __shfl_xor(t1, 32);
    int t2 = c2a + c2b;  t2 += __shfl_xor(t2, 32);
    int t3 = c3a + c3b;  t3 += __shfl_xor(t3, 32);

    __shared__ int red[4][TI];
    if (lane < 32) {
        red[w][n]      = base + t0;
        red[w][n + 32] = base + t1;
        red[w][n + 64] = base + t2;
        red[w][n + 96] = base + t3;
    }
    __syncthreads();
    if (threadIdx.x < TI) {
        const int ii = ibase + threadIdx.x;
        if (ii < N) {
            const int s = red[0][threadIdx.x] + red[1][threadIdx.x] +
                          red[2][threadIdx.x] + red[3][threadIdx.x];
            atomicAdd(&out[ii], s);
        }
    }
}

extern "C" void kernel_launch(void* const* d_in, const int* in_sizes, int n_in,
                              void* d_out, int out_size, void* d_ws, size_t ws_size,
                              hipStream_t stream) {
    const float* pc  = (const float*)d_in[0];   // [N,3] pointcloud
    const float* pad = (const float*)d_in[1];   // [M,3] pointcloud_padding
    int* out = (int*)d_out;

    const int N = in_sizes[0] / 3;              // 20000
    const int M = in_sizes[1] / 3;              // 25000
    const int jt = (M + 31) / 32;               // 782 j-tiles
    int visits = (jt + STREAMS - 1) / STREAMS;  // 16
    if (visits & 1) visits++;                   // 2-visit unrolled body
    const int jtp  = (visits + DEPTH) * STREAMS;    // 936 tiles incl. prefetch overrun
    const int mtot = jtp * 32;                  // 29952 rows (~958 KB in ws)

    dens_pack_kernel<<<(mtot + 255) / 256, 256, 0, stream>>>(
        pad, (uint4*)d_ws, out, M, mtot, N);

    dim3 grid((N + TI - 1) / TI, JS);           // 157 x 13
    dens_mfma_kernel<<<grid, 256, 0, stream>>>(
        pc, (const char*)d_ws, out, N, visits / 2, mtot * 16, visits);
}